// Round 15
// baseline (37.200 us; speedup 1.0000x reference)
//
#include <hip/hip_runtime.h>
#include <cstdint>
#include <math.h>

#define N_FRAMES 16777216          // 2^24
#define MAX_BEATS (N_FRAMES / 8)   // 2097152
#define CHUNK 4096
#define NTHREADS 256
#define NCHUNK (N_FRAMES / CHUNK)  // 4096
#define NBLK (NCHUNK / 4)          // 1024 emit blocks (4 waves, 1 chunk each)
#define TOTAL_MASKS ((size_t)NCHUNK * 64)
#define MAXSEC 2064                // >= max sections/chunk (2048) + pad

typedef unsigned long long u64;
typedef unsigned int u32;

__device__ __forceinline__ float max3f(float a, float b, float c) {
  return fmaxf(fmaxf(a, b), c);
}

// k_count: verbatim R11 winner.
__global__ __launch_bounds__(NTHREADS) void k_count(const float* __restrict__ x,
                                                    int* __restrict__ counts,
                                                    u64* __restrict__ masks) {
  __shared__ u32 m16[NTHREADS];
  __shared__ u32 s_pm1;
  const int b = blockIdx.x;
  const int t = threadIdx.x;
  const int lane = t & 63;
  const int gbase = b * CHUNK + t * 16;

  float v[23];
  {
    const float4* p = reinterpret_cast<const float4*>(x + gbase);
#pragma unroll
    for (int k = 0; k < 4; ++k) {
      const float4 f = p[k];
      v[4 + 4 * k] = f.x; v[5 + 4 * k] = f.y; v[6 + 4 * k] = f.z; v[7 + 4 * k] = f.w;
    }
  }
  v[0]  = __shfl_up(v[16], 1, 64);
  v[1]  = __shfl_up(v[17], 1, 64);
  v[2]  = __shfl_up(v[18], 1, 64);
  v[3]  = __shfl_up(v[19], 1, 64);
  v[20] = __shfl_down(v[4], 1, 64);
  v[21] = __shfl_down(v[5], 1, 64);
  v[22] = __shfl_down(v[6], 1, 64);
  if (lane == 0) {
    if (gbase >= 4) {
      const float4 f = *reinterpret_cast<const float4*>(x + gbase - 4);
      v[0] = f.x; v[1] = f.y; v[2] = f.z; v[3] = f.w;
    } else { v[0] = v[1] = v[2] = v[3] = -INFINITY; }
  }
  if (lane == 63) {
    if (gbase + 20 <= N_FRAMES) {
      const float4 f = *reinterpret_cast<const float4*>(x + gbase + 16);
      v[20] = f.x; v[21] = f.y; v[22] = f.z;
    } else { v[20] = v[21] = v[22] = -INFINITY; }
  }

  float Lt[21];
#pragma unroll
  for (int i = 0; i < 21; ++i) Lt[i] = max3f(v[i], v[i + 1], v[i + 2]);

  u32 pm = 0;
#pragma unroll
  for (int e = 0; e < 16; ++e) {
    const float c = v[e + 4];
    const float m = fmaxf(Lt[e + 1], Lt[e + 5]);
    if (c > 0.0f && c >= m) pm |= (1u << e);
  }
  m16[t] = pm;
  if (t == 0) {
    const float c = v[3];
    const float m = fmaxf(Lt[0], Lt[4]);
    s_pm1 = (c > 0.0f && c >= m) ? 1u : 0u;
  }
  __syncthreads();

  if (t < 64) {
    const u64 m = (u64)m16[4 * t] | ((u64)m16[4 * t + 1] << 16) |
                  ((u64)m16[4 * t + 2] << 32) | ((u64)m16[4 * t + 3] << 48);
    masks[((size_t)b << 6) + t] = m;
    const u64 carry = (t == 0) ? (u64)s_pm1 : (u64)((m16[4 * t - 1] >> 15) & 1u);
    int cnt = __popcll(m & ~((m << 1) | carry));
#pragma unroll
    for (int off = 32; off; off >>= 1) cnt += __shfl_down(cnt, off, 64);
    if (t == 0) counts[b] = cnt;
  }
}

// k_emit: verbatim R11 winner.
__global__ __launch_bounds__(NTHREADS) void k_emit(const u64* __restrict__ masks,
                                                   const int* __restrict__ counts,
                                                   float* __restrict__ out) {
  __shared__ float s_out[4][MAXSEC];
  __shared__ int s_wtot[4];
  __shared__ int s_texcl[NTHREADS];
  __shared__ int s_off[4];
  __shared__ int s_total;
  const int t = threadIdx.x, lane = t & 63, wv = t >> 6;

  int s = 0;
  const int cb = t * 16;
#pragma unroll
  for (int e = 0; e < 16; ++e) s += counts[cb + e];
  int incl = s;
#pragma unroll
  for (int off = 1; off < 64; off <<= 1) {
    const int vv = __shfl_up(incl, off, 64);
    if (lane >= off) incl += vv;
  }
  s_texcl[t] = incl - s;
  if (lane == 63) s_wtot[wv] = incl;
  __syncthreads();
  if (t == 0) s_total = s_wtot[0] + s_wtot[1] + s_wtot[2] + s_wtot[3];
  if (t < 4) {
    const int target = blockIdx.x * 4 + t;
    const int j = target >> 4, r = target & 15;
    int wb = 0;
    for (int ww = 0; ww < (j >> 6); ++ww) wb += s_wtot[ww];
    int pfx = wb + s_texcl[j];
    for (int e = 0; e < r; ++e) pfx += counts[j * 16 + e];
    s_off[t] = pfx;
  }
  __syncthreads();

  const int b = blockIdx.x * 4 + wv;
  const size_t mi = ((size_t)b << 6) + lane;
  const u64 m = masks[mi];
  const u32 myb63 = (u32)(m >> 63);
  u32 prevb = __shfl_up(myb63, 1, 64);
  if (lane == 0) prevb = (b == 0) ? 0u : (u32)(masks[mi - 1] >> 63);
  u64 sm = m & ~((m << 1) | (u64)prevb);
  const int cnt = __popcll(sm);

  int incl2 = cnt;
#pragma unroll
  for (int off = 1; off < 64; off <<= 1) {
    const int vv = __shfl_up(incl2, off, 64);
    if (lane >= off) incl2 += vv;
  }
  const int cnt_chunk = __shfl(incl2, 63, 64);
  int sidl = incl2 - cnt;

  if (s_off[wv] < MAX_BEATS) {
    const int gbase = b * CHUNK + lane * 64;
    u64 smw = sm;
    while (smw) {
      const int sb = __builtin_ctzll(smw);
      smw &= smw - 1;
      const int i0 = gbase + sb;
      const u64 above = m >> sb;
      const int len = (~above == 0ull) ? (64 - sb) : __builtin_ctzll(~above);
      int end = i0 + len - 1;
      if (sb + len == 64) {                // run continues into next mask (ties; rare)
        size_t idx = mi + 1;
        while (idx < TOTAL_MASKS) {
          const u64 mm = masks[idx];
          if (~mm == 0ull) { end += 64; ++idx; }
          else { end += __builtin_ctzll(~mm); break; }
        }
      }
      s_out[wv][sidl] = (float)(((double)i0 + (double)end) * 0.5);
      ++sidl;
    }
  }
  __syncthreads();

  if (s_off[wv] < MAX_BEATS) {
    const int off0 = s_off[wv];
    for (int i = lane; i < cnt_chunk; i += 64) {
      const int gi = off0 + i;
      if (gi < MAX_BEATS) out[gi] = s_out[wv][i];
    }
  }

  const int lo = blockIdx.x * (MAX_BEATS / NBLK);
  const int hi = lo + (MAX_BEATS / NBLK);
  for (int i = max(lo, s_total) + t; i < hi; i += NTHREADS)
    out[i] = -1.0f;
}

// overhead probe: real dispatch, no work
__global__ void k_empty() {}

extern "C" void kernel_launch(void* const* d_in, const int* in_sizes, int n_in,
                              void* d_out, int out_size, void* d_ws, size_t ws_size,
                              hipStream_t stream) {
  const float* x = (const float*)d_in[0];
  float* out = (float*)d_out;

  u64* masks = (u64*)d_ws;                      // 2 MiB
  int* counts = (int*)(masks + TOTAL_MASKS);    // 16 KiB

  // ATTRIBUTION PROBE: dur - 26.72 = T_emit + 2*launch_overhead.
  // (second k_emit rewrites identical values; k_empty isolates overhead)
  k_count<<<NCHUNK, NTHREADS, 0, stream>>>(x, counts, masks);
  k_emit<<<NBLK, NTHREADS, 0, stream>>>(masks, counts, out);
  k_emit<<<NBLK, NTHREADS, 0, stream>>>(masks, counts, out);
  k_empty<<<1, 64, 0, stream>>>();
}

// Round 16
// 26.627 us; speedup vs baseline: 1.3971x; 1.3971x over previous
//
#include <hip/hip_runtime.h>
#include <cstdint>
#include <math.h>

#define N_FRAMES 16777216          // 2^24
#define MAX_BEATS (N_FRAMES / 8)   // 2097152
#define CHUNK 4096
#define NTHREADS 256
#define NCHUNK (N_FRAMES / CHUNK)  // 4096
#define NBLK (NCHUNK / 4)          // 1024 emit blocks (4 waves, 1 chunk each)
#define TOTAL_MASKS ((size_t)NCHUNK * 64)
#define MAXSEC 2064                // >= max sections/chunk (2048) + pad

typedef unsigned long long u64;
typedef unsigned int u32;

__device__ __forceinline__ float max3f(float a, float b, float c) {
  return fmaxf(fmaxf(a, b), c);
}

// k_count: verbatim R11 winner (measured ~10.4 us warm; at its vmem-issue floor).
__global__ __launch_bounds__(NTHREADS) void k_count(const float* __restrict__ x,
                                                    int* __restrict__ counts,
                                                    u64* __restrict__ masks) {
  __shared__ u32 m16[NTHREADS];
  __shared__ u32 s_pm1;
  const int b = blockIdx.x;
  const int t = threadIdx.x;
  const int lane = t & 63;
  const int gbase = b * CHUNK + t * 16;

  float v[23];
  {
    const float4* p = reinterpret_cast<const float4*>(x + gbase);
#pragma unroll
    for (int k = 0; k < 4; ++k) {
      const float4 f = p[k];
      v[4 + 4 * k] = f.x; v[5 + 4 * k] = f.y; v[6 + 4 * k] = f.z; v[7 + 4 * k] = f.w;
    }
  }
  v[0]  = __shfl_up(v[16], 1, 64);
  v[1]  = __shfl_up(v[17], 1, 64);
  v[2]  = __shfl_up(v[18], 1, 64);
  v[3]  = __shfl_up(v[19], 1, 64);
  v[20] = __shfl_down(v[4], 1, 64);
  v[21] = __shfl_down(v[5], 1, 64);
  v[22] = __shfl_down(v[6], 1, 64);
  if (lane == 0) {
    if (gbase >= 4) {
      const float4 f = *reinterpret_cast<const float4*>(x + gbase - 4);
      v[0] = f.x; v[1] = f.y; v[2] = f.z; v[3] = f.w;
    } else { v[0] = v[1] = v[2] = v[3] = -INFINITY; }
  }
  if (lane == 63) {
    if (gbase + 20 <= N_FRAMES) {
      const float4 f = *reinterpret_cast<const float4*>(x + gbase + 16);
      v[20] = f.x; v[21] = f.y; v[22] = f.z;
    } else { v[20] = v[21] = v[22] = -INFINITY; }
  }

  float Lt[21];
#pragma unroll
  for (int i = 0; i < 21; ++i) Lt[i] = max3f(v[i], v[i + 1], v[i + 2]);

  u32 pm = 0;
#pragma unroll
  for (int e = 0; e < 16; ++e) {
    const float c = v[e + 4];
    const float m = fmaxf(Lt[e + 1], Lt[e + 5]);
    if (c > 0.0f && c >= m) pm |= (1u << e);
  }
  m16[t] = pm;
  if (t == 0) {
    const float c = v[3];
    const float m = fmaxf(Lt[0], Lt[4]);
    s_pm1 = (c > 0.0f && c >= m) ? 1u : 0u;
  }
  __syncthreads();

  if (t < 64) {
    const u64 m = (u64)m16[4 * t] | ((u64)m16[4 * t + 1] << 16) |
                  ((u64)m16[4 * t + 2] << 32) | ((u64)m16[4 * t + 3] << 48);
    masks[((size_t)b << 6) + t] = m;
    const u64 carry = (t == 0) ? (u64)s_pm1 : (u64)((m16[4 * t - 1] >> 15) & 1u);
    int cnt = __popcll(m & ~((m << 1) | carry));
#pragma unroll
    for (int off = 32; off; off >>= 1) cnt += __shfl_down(cnt, off, 64);
    if (t == 0) counts[b] = cnt;
  }
}

// k_emit v3: wave wv owns chunk blockIdx.x + 1024*wv (XCD-aligned with k_count's
// producer). Chunk offsets come from the owning scan-thread's REGISTERS (no
// serial global remainder loads). Sections staged in LDS, coalesced flush.
__global__ __launch_bounds__(NTHREADS) void k_emit(const u64* __restrict__ masks,
                                                   const int* __restrict__ counts,
                                                   float* __restrict__ out) {
  __shared__ float s_out[4][MAXSEC];
  __shared__ int s_wtot[4];
  __shared__ int s_off[4];
  __shared__ int s_total;
  const int t = threadIdx.x, lane = t & 63, wv = t >> 6;
  const int B = blockIdx.x;

  // scan phase: thread t holds counts[16t .. 16t+16) in registers
  int local[16];
  int s = 0;
  {
    const int cb = t * 16;
#pragma unroll
    for (int e = 0; e < 16; ++e) { local[e] = counts[cb + e]; s += local[e]; }
  }
  int incl = s;
#pragma unroll
  for (int off = 1; off < 64; off <<= 1) {
    const int vv = __shfl_up(incl, off, 64);
    if (lane >= off) incl += vv;
  }
  const int texcl = incl - s;          // exclusive prefix within this wave
  if (lane == 63) s_wtot[wv] = incl;
  __syncthreads();
  if (t == 0) s_total = s_wtot[0] + s_wtot[1] + s_wtot[2] + s_wtot[3];
  // chunk c_w = B + 1024*w has j = c_w>>4 = (B>>4)+64*w (thread j in wave w),
  // r = c_w&15 = B&15 (uniform). Qualifying thread uses its OWN registers.
  if ((t & 63) == (B >> 4)) {
    int wb = 0;
    for (int ww = 0; ww < wv; ++ww) wb += s_wtot[ww];
    const int r = B & 15;
    int part = 0;
#pragma unroll
    for (int e = 0; e < 16; ++e) part += (e < r) ? local[e] : 0;
    s_off[wv] = wb + texcl + part;
  }
  __syncthreads();

  const int b = B + 1024 * wv;         // XCD-aligned chunk for this wave
  const size_t mi = ((size_t)b << 6) + lane;
  const u64 m = masks[mi];
  const u32 myb63 = (u32)(m >> 63);
  u32 prevb = __shfl_up(myb63, 1, 64);
  if (lane == 0) prevb = (b == 0) ? 0u : (u32)(masks[mi - 1] >> 63);
  u64 sm = m & ~((m << 1) | (u64)prevb);
  const int cnt = __popcll(sm);

  int incl2 = cnt;
#pragma unroll
  for (int off = 1; off < 64; off <<= 1) {
    const int vv = __shfl_up(incl2, off, 64);
    if (lane >= off) incl2 += vv;
  }
  const int cnt_chunk = __shfl(incl2, 63, 64);
  int sidl = incl2 - cnt;

  if (s_off[wv] < MAX_BEATS) {
    const int gbase = b * CHUNK + lane * 64;
    u64 smw = sm;
    while (smw) {
      const int sb = __builtin_ctzll(smw);
      smw &= smw - 1;
      const int i0 = gbase + sb;
      const u64 above = m >> sb;
      const int len = (~above == 0ull) ? (64 - sb) : __builtin_ctzll(~above);
      int end = i0 + len - 1;
      if (sb + len == 64) {                // run continues into next mask (ties; rare)
        size_t idx = mi + 1;
        while (idx < TOTAL_MASKS) {
          const u64 mm = masks[idx];
          if (~mm == 0ull) { end += 64; ++idx; }
          else { end += __builtin_ctzll(~mm); break; }
        }
      }
      s_out[wv][sidl] = (float)(((double)i0 + (double)end) * 0.5);
      ++sidl;
    }
  }
  __syncthreads();

  if (s_off[wv] < MAX_BEATS) {
    const int off0 = s_off[wv];
    for (int i = lane; i < cnt_chunk; i += 64) {
      const int gi = off0 + i;
      if (gi < MAX_BEATS) out[gi] = s_out[wv][i];
    }
  }

  // -1 tail fill: this block covers out[B*2048 .. +2048)
  const int lo = B * (MAX_BEATS / NBLK);
  const int hi = lo + (MAX_BEATS / NBLK);
  for (int i = max(lo, s_total) + t; i < hi; i += NTHREADS)
    out[i] = -1.0f;
}

extern "C" void kernel_launch(void* const* d_in, const int* in_sizes, int n_in,
                              void* d_out, int out_size, void* d_ws, size_t ws_size,
                              hipStream_t stream) {
  const float* x = (const float*)d_in[0];
  float* out = (float*)d_out;

  u64* masks = (u64*)d_ws;                      // 2 MiB
  int* counts = (int*)(masks + TOTAL_MASKS);    // 16 KiB

  k_count<<<NCHUNK, NTHREADS, 0, stream>>>(x, counts, masks);
  k_emit<<<NBLK, NTHREADS, 0, stream>>>(masks, counts, out);
}